// Round 6
// baseline (866.686 us; speedup 1.0000x reference)
//
#include <hip/hip_runtime.h>
#include <math.h>

typedef unsigned short u16;
typedef unsigned int   u32;
typedef __bf16 bf16_t;
typedef bf16_t bf16x8 __attribute__((ext_vector_type(8)));
typedef float  f32x4  __attribute__((ext_vector_type(4)));
typedef u16    u16x8  __attribute__((ext_vector_type(8)));
typedef u16    u16x4  __attribute__((ext_vector_type(4)));

#define B_   8
#define L_   1024
#define DIN_ 32
#define D_   512
#define H_   8
#define NL_  6
#define FF_  64
#define M_   (B_*L_)    // 8192
#define DD_  (D_*D_)    // 262144

#define PE_COEF (-0.017988946039015984f)   // -ln(10000)/512
#define SC2     (0.18033688011112042f)     // 0.125 * log2(e)

__device__ __forceinline__ u16 f2bf(float f) {
  u32 u = __builtin_bit_cast(u32, f);
  u32 r = (u + 0x7FFFu + ((u >> 16) & 1u)) >> 16;
  return (u16)r;
}
__device__ __forceinline__ u16 f2bf_fast(float f) {   // positive values (P in [0,1])
  u32 u = __builtin_bit_cast(u32, f);
  return (u16)((u + 0x8000u) >> 16);
}
__device__ __forceinline__ float bf2f(u16 v) {
  u32 u = ((u32)v) << 16;
  return __builtin_bit_cast(float, u);
}

#define GLOAD_LDS16(gp, lp) \
  __builtin_amdgcn_global_load_lds((const __attribute__((address_space(1))) u32*)(gp), \
                                   (__attribute__((address_space(3))) u32*)(lp), 16, 0, 0)

// ---------------- fused weight transpose + f32->bf16 for all 512x512 sets ----------------
// z: 0-5 wq, 6-11 wk, 12-17 wv, 18-23 wo, 24 emb_w2.  W[K][N] -> Wt[N][K].
__global__ __launch_bounds__(256) void transpose_all(const float* __restrict__ wq, const float* __restrict__ wk,
                                                     const float* __restrict__ wv, const float* __restrict__ wo,
                                                     const float* __restrict__ ew2,
                                                     u16* __restrict__ qkvt, u16* __restrict__ wot,
                                                     u16* __restrict__ ew2t) {
  __shared__ float tile[32][33];
  int z = blockIdx.z;
  const float* src;
  u16* dst;
  if (z < 18) {
    int grp = z / 6, i = z % 6;
    src = (grp == 0 ? wq : grp == 1 ? wk : wv) + (size_t)i*DD_;
    dst = qkvt + (size_t)i*3*DD_ + (size_t)grp*DD_;
  } else if (z < 24) {
    int i = z - 18;
    src = wo + (size_t)i*DD_;
    dst = wot + (size_t)i*DD_;
  } else {
    src = ew2; dst = ew2t;
  }
  int k0 = blockIdx.y * 32, n0 = blockIdx.x * 32;
  int tx = threadIdx.x & 31, ty = threadIdx.x >> 5;
  #pragma unroll
  for (int i = 0; i < 4; ++i)
    tile[ty + i*8][tx] = src[(size_t)(k0 + ty + i*8)*512 + n0 + tx];
  __syncthreads();
  #pragma unroll
  for (int i = 0; i < 4; ++i)
    dst[(size_t)(n0 + ty + i*8)*512 + k0 + tx] = f2bf(tile[tx][ty + i*8]);
}

// ---------------- generic weight transpose (fw1/fw2) ----------------
__global__ __launch_bounds__(256) void transpose_k(const float* __restrict__ W, u16* __restrict__ Wt,
                                                   int K, int N, size_t in_zs, size_t out_zs) {
  __shared__ float tile[32][33];
  size_t mi = (size_t)blockIdx.z * in_zs;
  size_t mo = (size_t)blockIdx.z * out_zs;
  int k0 = blockIdx.y * 32, n0 = blockIdx.x * 32;
  int tx = threadIdx.x & 31, ty = threadIdx.x >> 5;
  #pragma unroll
  for (int i = 0; i < 4; ++i)
    tile[ty + i*8][tx] = W[mi + (size_t)(k0 + ty + i*8)*N + n0 + tx];
  __syncthreads();
  #pragma unroll
  for (int i = 0; i < 4; ++i)
    Wt[mo + (size_t)(n0 + ty + i*8)*K + k0 + tx] = f2bf(tile[tx][ty + i*8]);
}

// ---------------- embedding MLP stage 1 + LayerNorm (bf16 out) ----------------
__global__ __launch_bounds__(256) void emb1_ln_kernel(const float* __restrict__ x, const float* __restrict__ W1,
                               const float* __restrict__ b1, const float* __restrict__ g,
                               const float* __restrict__ beta, u16* __restrict__ outb) {
  __shared__ float xs[DIN_];
  __shared__ float red[4];
  int m = blockIdx.x;
  int tid = threadIdx.x;
  if (tid < DIN_) xs[tid] = x[m*DIN_ + tid];
  __syncthreads();
  float v[2];
  #pragma unroll
  for (int r = 0; r < 2; ++r) {
    int n = tid + r*256;
    float acc = b1[n];
    #pragma unroll
    for (int k = 0; k < DIN_; ++k) acc += xs[k] * W1[k*D_ + n];
    v[r] = fmaxf(acc, 0.f);
  }
  // block reduce
  float s = v[0] + v[1];
  #pragma unroll
  for (int off = 32; off > 0; off >>= 1) s += __shfl_down(s, off, 64);
  int wid = tid >> 6;
  if ((tid & 63) == 0) red[wid] = s;
  __syncthreads();
  float mean = (red[0] + red[1] + red[2] + red[3]) * (1.f/D_);
  float d0 = v[0] - mean, d1 = v[1] - mean;
  float vv = d0*d0 + d1*d1;
  #pragma unroll
  for (int off = 32; off > 0; off >>= 1) vv += __shfl_down(vv, off, 64);
  __syncthreads();
  if ((tid & 63) == 0) red[wid] = vv;
  __syncthreads();
  float var = (red[0] + red[1] + red[2] + red[3]) * (1.f/D_);
  float rstd = rsqrtf(var + 1e-5f);
  outb[(size_t)m*D_ + tid]       = f2bf(d0*rstd*g[tid]       + beta[tid]);
  outb[(size_t)m*D_ + tid + 256] = f2bf(d1*rstd*g[tid + 256] + beta[tid + 256]);
}

// ---------------- residual add + LayerNorm, one wave per row ----------------
__global__ __launch_bounds__(256) void add_ln_kernel(const float* __restrict__ hin, const u16* __restrict__ res,
                              const float* __restrict__ g, const float* __restrict__ b,
                              float* __restrict__ outf, u16* __restrict__ outb) {
  int w = threadIdx.x >> 6, lane = threadIdx.x & 63;
  int m = blockIdx.x * 4 + w;
  const float* hr = hin + (size_t)m*D_;
  const u16*   rr = res + (size_t)m*D_;
  float v[8];
  float s = 0.f;
  #pragma unroll
  for (int i = 0; i < 8; ++i) {
    int c = lane + i*64;
    v[i] = hr[c] + bf2f(rr[c]);
    s += v[i];
  }
  #pragma unroll
  for (int off = 32; off > 0; off >>= 1) s += __shfl_xor(s, off, 64);
  float mean = s * (1.f/D_);
  float vs = 0.f;
  #pragma unroll
  for (int i = 0; i < 8; ++i) { v[i] -= mean; vs += v[i]*v[i]; }
  #pragma unroll
  for (int off = 32; off > 0; off >>= 1) vs += __shfl_xor(vs, off, 64);
  float rstd = rsqrtf(vs * (1.f/D_) + 1e-5f);
  #pragma unroll
  for (int i = 0; i < 8; ++i) {
    int c = lane + i*64;
    float o = v[i]*rstd*g[c] + b[c];
    outf[(size_t)m*D_ + c] = o;
    outb[(size_t)m*D_ + c] = f2bf(o);
  }
}

// ---------------- bf16 MFMA GEMM, BK=64 2-phase pipeline, XOR-swizzled LDS ----------------
// C = A[M,K] @ Bt[N,K]^T.  EPI bits: 1=+bias, 2=relu, 4=+PE.  WF: f32 out, WB: bf16 out.
// Swizzle (both-sides involution, rule #21): global source segment col8 ^= (row&1)<<2,
// LDS dest linear; read recovers k-half h via h ^ (lq&1).
template<int BM, int BN, int EPI, bool WF, bool WB>
__global__ __launch_bounds__(256) void mgemm(const u16* __restrict__ A, const u16* __restrict__ Bt,
                            const float* __restrict__ bias, const float* __restrict__ extra,
                            float* __restrict__ Cf, u16* __restrict__ Cb,
                            int M, int N, int K) {
  constexpr int BK = 64;
  constexpr int AI = BM/32, BI = BN/32;    // global_load_lds instructions per stage
  __shared__ __align__(16) u16 As[2][BM*BK];
  __shared__ __align__(16) u16 Bs[2][BN*BK];
  const int WR = BM/2, WC = BN/2, MR = WR/16, NR = WC/16;
  // XCD-chunked swizzle (all grids have nwg % 8 == 0)
  int nx = gridDim.x;
  int nwg = nx * gridDim.y;
  int flat = blockIdx.y * nx + blockIdx.x;
  int wid = (flat & 7) * (nwg >> 3) + (flat >> 3);
  int bm = (wid / nx) * BM, bn = (wid % nx) * BN;
  int tid = threadIdx.x, w = tid >> 6, l = tid & 63;
  int wr = w >> 1, wc = w & 1;
  int lq = l & 15, lg = l >> 4;
  int lrow8 = l >> 3, lcol8 = l & 7;
  f32x4 acc[MR][NR];
  #pragma unroll
  for (int m = 0; m < MR; ++m)
    #pragma unroll
    for (int n = 0; n < NR; ++n) acc[m][n] = f32x4{0.f,0.f,0.f,0.f};

  auto stage = [&](int t, int bi) {
    int k0 = t * BK;
    #pragma unroll
    for (int i = 0; i < AI; ++i) {
      int row = (i*4 + w)*8 + lrow8;
      int c8 = lcol8 ^ ((row & 1) << 2);
      GLOAD_LDS16(A + (size_t)(bm + row)*K + k0 + c8*8, &As[bi][(i*4 + w)*512]);
    }
    #pragma unroll
    for (int i = 0; i < BI; ++i) {
      int row = (i*4 + w)*8 + lrow8;
      int c8 = lcol8 ^ ((row & 1) << 2);
      GLOAD_LDS16(Bt + (size_t)(bn + row)*K + k0 + c8*8, &Bs[bi][(i*4 + w)*512]);
    }
  };

  int nk = K / BK;
  stage(0, 0);
  asm volatile("s_waitcnt vmcnt(0)" ::: "memory");
  __builtin_amdgcn_s_barrier();
  __builtin_amdgcn_sched_barrier(0);

  int xh = lq & 1;
  #pragma unroll 1
  for (int t = 0; t < nk; ++t) {
    int buf = t & 1;
    if (t + 1 < nk) stage(t + 1, buf ^ 1);   // in flight during this tile's compute
    bf16x8 af[MR][2], bf[NR][2];
    #pragma unroll
    for (int m = 0; m < MR; ++m)
      #pragma unroll
      for (int h = 0; h < 2; ++h)
        af[m][h] = *(const bf16x8*)&As[buf][(wr*WR + m*16 + lq)*BK + (h ^ xh)*32 + lg*8];
    #pragma unroll
    for (int n = 0; n < NR; ++n)
      #pragma unroll
      for (int h = 0; h < 2; ++h)
        bf[n][h] = *(const bf16x8*)&Bs[buf][(wc*WC + n*16 + lq)*BK + (h ^ xh)*32 + lg*8];
    #pragma unroll
    for (int m = 0; m < MR; ++m)
      #pragma unroll
      for (int n = 0; n < NR; ++n) {
        acc[m][n] = __builtin_amdgcn_mfma_f32_16x16x32_bf16(af[m][0], bf[n][0], acc[m][n], 0, 0, 0);
        acc[m][n] = __builtin_amdgcn_mfma_f32_16x16x32_bf16(af[m][1], bf[n][1], acc[m][n], 0, 0, 0);
      }
    if (t + 1 < nk) {
      asm volatile("s_waitcnt vmcnt(0)" ::: "memory");  // stage(t+1) landed
      __builtin_amdgcn_s_barrier();
      __builtin_amdgcn_sched_barrier(0);                 // keep next stage below barrier
    }
  }

  #pragma unroll
  for (int m = 0; m < MR; ++m) {
    #pragma unroll
    for (int n = 0; n < NR; ++n) {
      #pragma unroll
      for (int r = 0; r < 4; ++r) {
        int row = bm + wr*WR + m*16 + lg*4 + r;
        int col = bn + wc*WC + n*16 + lq;
        float v = acc[m][n][r];
        if (EPI & 1) v += bias[col];
        if (EPI & 2) v = fmaxf(v, 0.f);
        if (EPI & 4) {
          float fr  = __expf((float)(col & ~1) * PE_COEF);
          float arg = extra[row] * fr;
          v += (col & 1) ? cosf(arg) : sinf(arg);
        }
        if (WF) Cf[(size_t)row*N + col] = v;
        if (WB) Cb[(size_t)row*N + col] = f2bf(v);
      }
    }
  }
}

// ---------------- MFMA causal flash attention, KVBLK=64, paired q-tiles ----------------
#define QS_ 1536
__global__ __launch_bounds__(256) void attn_kernel(const u16* __restrict__ Q, const u16* __restrict__ Kp,
                                                   const u16* __restrict__ V, u16* __restrict__ O) {
  __shared__ __align__(16) u16 Ks[2][64*72];     // [kv][d]  stride 72
  __shared__ __align__(16) u16 Vt[2][64*72];     // [d][kv]  stride 72
  __shared__ __align__(16) u16 Ps[4][16*72];     // per-wave [q][kv] stride 72
  int flat = blockIdx.y * 8 + blockIdx.x;        // grid (8,64), nwg=512
  int wid  = (flat & 7) * 64 + (flat >> 3);
  int pair = wid & 7, bh = wid >> 3;
  int b = bh >> 3, hh = bh & 7;
  int rowbase = b * L_, col0 = hh * 64;
  int tid = threadIdx.x, w = tid >> 6, l = tid & 63;
  int lq = l & 15, lg = l >> 4;

  int krow = tid >> 3, kseg = tid & 7;
  int vg = tid >> 5, vd2 = (tid & 31) * 2;

  u16x8 kr0, kr1;
  u32 vr[8];
  u16x8 oc16;
  #pragma unroll
  for (int i = 0; i < 8; ++i) oc16[i] = 0x3F80u;   // bf16 1.0
  const bf16x8 onesA = __builtin_bit_cast(bf16x8, oc16);

  #define LOADKV(t) { \
    kr0 = *(const u16x8*)&Kp[(size_t)(rowbase + (t)*64 + krow)*QS_ + col0 + kseg*8]; \
    kr1 = *(const u16x8*)&Kp[(size_t)(rowbase + (t)*64 + krow + 32)*QS_ + col0 + kseg*8]; \
    _Pragma("unroll") \
    for (int i_ = 0; i_ < 8; ++i_) \
      vr[i_] = *(const u32*)&V[(size_t)(rowbase + (t)*64 + vg*8 + i_)*QS_ + col0 + vd2]; }

  LOADKV(0);

  #pragma unroll 1
  for (int half = 0; half < 2; ++half) {
    int qt = half ? (15 - pair) : pair;
    int qrow = rowbase + qt*64 + w*16 + lq;
    bf16x8 qa0 = *(const bf16x8*)&Q[(size_t)qrow*QS_ + col0 + lg*8];
    bf16x8 qa1 = *(const bf16x8*)&Q[(size_t)qrow*QS_ + col0 + 32 + lg*8];
    float m_s[4];
    f32x4 o[4], o4;
    #pragma unroll
    for (int r = 0; r < 4; ++r) m_s[r] = -1e30f;
    #pragma unroll
    for (int n = 0; n < 4; ++n) o[n] = f32x4{0.f,0.f,0.f,0.f};
    o4 = f32x4{0.f,0.f,0.f,0.f};

    #pragma unroll 1
    for (int kt = 0; kt <= qt; ++kt) {
      int buf = kt & 1;
      __syncthreads();
      *(u16x8*)&Ks[buf][krow*72 + kseg*8]        = kr0;
      *(u16x8*)&Ks[buf][(krow + 32)*72 + kseg*8] = kr1;
      {
        u16x8 vlo, vhi;
        #pragma unroll
        for (int i = 0; i < 8; ++i) { vlo[i] = (u16)(vr[i] & 0xffffu); vhi[i] = (u16)(vr[i] >> 16); }
        *(u16x8*)&Vt[buf][vd2*72 + vg*8]     = vlo;
        *(u16x8*)&Vt[buf][(vd2+1)*72 + vg*8] = vhi;
      }
      __syncthreads();
      int nt = (kt < qt) ? (kt + 1) : (half == 0 ? 0 : -1);
      if (nt >= 0) LOADKV(nt);

      f32x4 t4[4];
      __builtin_amdgcn_s_setprio(1);
      #pragma unroll
      for (int f = 0; f < 4; ++f) {
        bf16x8 k0 = *(const bf16x8*)&Ks[buf][(f*16 + lq)*72 + lg*8];
        bf16x8 k1 = *(const bf16x8*)&Ks[buf][(f*16 + lq)*72 + 32 + lg*8];
        f32x4 z = f32x4{0.f,0.f,0.f,0.f};
        z = __builtin_amdgcn_mfma_f32_16x16x32_bf16(qa0, k0, z, 0, 0, 0);
        z = __builtin_amdgcn_mfma_f32_16x16x32_bf16(qa1, k1, z, 0, 0, 0);
        #pragma unroll
        for (int r = 0; r < 4; ++r) t4[f][r] = z[r] * SC2;
      }
      __builtin_amdgcn_s_setprio(0);
      if (kt == qt) {
        #pragma unroll
        for (int f = 0; f < 4; ++f) {
          int kvg = f*16 + lq;
          #pragma unroll
          for (int r = 0; r < 4; ++r)
            if (kvg > w*16 + lg*4 + r) t4[f][r] = -1e30f;
        }
      }
      float tm[4];
      bool need = false;
      #pragma unroll
      for (int r = 0; r < 4; ++r) {
        float v = fmaxf(fmaxf(t4[0][r], t4[1][r]), fmaxf(t4[2][r], t4[3][r]));
        v = fmaxf(v, __shfl_xor(v, 1));
        v = fmaxf(v, __shfl_xor(v, 2));
        v = fmaxf(v, __shfl_xor(v, 4));
        v = fmaxf(v, __shfl_xor(v, 8));
        tm[r] = v;
        need = need || (v > m_s[r]);
      }
      if (__any(need)) {
        float corr[4];
        #pragma unroll
        for (int r = 0; r < 4; ++r) {
          float mn = fmaxf(m_s[r], tm[r]);
          corr[r] = __builtin_amdgcn_exp2f(m_s[r] - mn);
          m_s[r] = mn;
        }
        int bsrc = (lq >> 2)*16 + lq;
        float c0 = __shfl(corr[0], bsrc);
        float c1 = __shfl(corr[1], bsrc);
        float c2 = __shfl(corr[2], bsrc);
        float c3 = __shfl(corr[3], bsrc);
        float cb = (lq & 2) ? ((lq & 1) ? c3 : c2) : ((lq & 1) ? c1 : c0);
        #pragma unroll
        for (int n = 0; n < 4; ++n)
          #pragma unroll
          for (int r = 0; r < 4; ++r) o[n][r] *= cb;
        #pragma unroll
        for (int r = 0; r < 4; ++r) o4[r] *= cb;
      }
      #pragma unroll
      for (int r = 0; r < 4; ++r) {
        int prow = (lg*4 + r)*72;
        Ps[w][prow + lq]      = f2bf_fast(__builtin_amdgcn_exp2f(t4[0][r] - m_s[r]));
        Ps[w][prow + 16 + lq] = f2bf_fast(__builtin_amdgcn_exp2f(t4[1][r] - m_s[r]));
        Ps[w][prow + 32 + lq] = f2bf_fast(__builtin_amdgcn_exp2f(t4[2][r] - m_s[r]));
        Ps[w][prow + 48 + lq] = f2bf_fast(__builtin_amdgcn_exp2f(t4[3][r] - m_s[r]));
      }
      bf16x8 pB0 = *(const bf16x8*)&Ps[w][lq*72 + lg*8];
      bf16x8 pB1 = *(const bf16x8*)&Ps[w][lq*72 + 32 + lg*8];
      __builtin_amdgcn_s_setprio(1);
      o4 = __builtin_amdgcn_mfma_f32_16x16x32_bf16(onesA, pB0, o4, 0, 0, 0);
      o4 = __builtin_amdgcn_mfma_f32_16x16x32_bf16(onesA, pB1, o4, 0, 0, 0);
      #pragma unroll
      for (int n = 0; n < 4; ++n) {
        bf16x8 vA0 = *(const bf16x8*)&Vt[buf][(n*16 + lq)*72 + lg*8];
        bf16x8 vA1 = *(const bf16x8*)&Vt[buf][(n*16 + lq)*72 + 32 + lg*8];
        o[n] = __builtin_amdgcn_mfma_f32_16x16x32_bf16(vA0, pB0, o[n], 0, 0, 0);
        o[n] = __builtin_amdgcn_mfma_f32_16x16x32_bf16(vA1, pB1, o[n], 0, 0, 0);
      }
      __builtin_amdgcn_s_setprio(0);
    }
    float inv = 1.f / o4[0];
    #pragma unroll
    for (int n = 0; n < 4; ++n) {
      u16x4 pk;
      #pragma unroll
      for (int r = 0; r < 4; ++r) pk[r] = f2bf(o[n][r] * inv);
      *(u16x4*)&O[(size_t)(rowbase + qt*64 + w*16 + lq)*D_ + col0 + n*16 + lg*4] = pk;
    }
  }
  #undef LOADKV
}

// ---------------- host ----------------
extern "C" void kernel_launch(void* const* d_in, const int* in_sizes, int n_in,
                              void* d_out, int out_size, void* d_ws, size_t ws_size,
                              hipStream_t stream) {
  (void)in_sizes; (void)n_in; (void)out_size; (void)ws_size;
  const float* x      = (const float*)d_in[0];
  const float* obs    = (const float*)d_in[2];
  const float* emb_w1 = (const float*)d_in[3];
  const float* emb_b1 = (const float*)d_in[4];
  const float* emb_g  = (const float*)d_in[5];
  const float* emb_be = (const float*)d_in[6];
  const float* emb_w2 = (const float*)d_in[7];
  const float* emb_b2 = (const float*)d_in[8];
  const float* wq  = (const float*)d_in[9];
  const float* wk  = (const float*)d_in[10];
  const float* wv  = (const float*)d_in[11];
  const float* wo  = (const float*)d_in[12];
  const float* bo  = (const float*)d_in[13];
  const float* fw1 = (const float*)d_in[14];
  const float* fb1 = (const float*)d_in[15];
  const float* fw2 = (const float*)d_in[16];
  const float* fb2 = (const float*)d_in[17];
  const float* g1  = (const float*)d_in[18];
  const float* b1  = (const float*)d_in[19];
  const float* g2  = (const float*)d_in[20];
  const float* b2  = (const float*)d_in[21];
  float* out = (float*)d_out;

  float* hf  = (float*)d_ws;                  // [M,D] f32 residual
  u16* hb    = (u16*)(hf + (size_t)M_*D_);    // [M,D] bf16 copy of hf
  u16* qkvb  = hb + (size_t)M_*D_;            // [M,3D] bf16 fused qkv
  u16* ob    = qkvb + (size_t)M_*3*D_;        // [M,D] bf16 (emb1 out / attn out)
  u16* ofb   = ob + (size_t)M_*D_;            // [M,D] bf16 branch out
  u16* fhb   = ofb + (size_t)M_*D_;           // [M,FF] bf16
  u16* qkvt  = fhb + (size_t)M_*FF_;          // [NL][3][D][D] bf16 (W^T)
  u16* wot   = qkvt + (size_t)18*DD_;         // [NL][D][D]
  u16* ew2t  = wot + (size_t)6*DD_;           // [D][D]
  u16* fw1t  = ew2t + (size_t)DD_;            // [NL][FF][D]
  u16* fw2t  = fw1t + (size_t)6*D_*FF_;       // [NL][D][FF]

  transpose_all<<<dim3(16,16,25), 256, 0, stream>>>(wq, wk, wv, wo, emb_w2, qkvt, wot, ew2t);
  transpose_k<<<dim3(2,16,6),  256, 0, stream>>>(fw1, fw1t, 512,  64, (size_t)D_*FF_, (size_t)D_*FF_);
  transpose_k<<<dim3(16,2,6),  256, 0, stream>>>(fw2, fw2t,  64, 512, (size_t)D_*FF_, (size_t)D_*FF_);

  emb1_ln_kernel<<<M_, 256, 0, stream>>>(x, emb_w1, emb_b1, emb_g, emb_be, ob);
  mgemm<128,128,5,true,true><<<dim3(4,64), 256, 0, stream>>>(ob, ew2t, emb_b2, obs, hf, hb, M_, D_, D_);

  for (int i = 0; i < NL_; ++i) {
    mgemm<128,128,0,false,true><<<dim3(12,64), 256, 0, stream>>>(hb, qkvt + (size_t)i*3*DD_,
        nullptr, nullptr, nullptr, qkvb, M_, 3*D_, D_);
    attn_kernel<<<dim3(8, B_*H_), 256, 0, stream>>>(qkvb, qkvb + D_, qkvb + 2*D_, ob);
    mgemm<128,128,1,false,true><<<dim3(4,64), 256, 0, stream>>>(ob, wot + (size_t)i*DD_,
        bo + i*D_, nullptr, nullptr, ofb, M_, D_, D_);
    add_ln_kernel<<<M_/4, 256, 0, stream>>>(hf, ofb, g1 + i*D_, b1 + i*D_, hf, hb);
    mgemm<64,64,3,false,true><<<dim3(1,128), 256, 0, stream>>>(hb, fw1t + (size_t)i*D_*FF_,
        fb1 + i*FF_, nullptr, nullptr, fhb, M_, FF_, D_);
    mgemm<128,128,1,false,true><<<dim3(4,64), 256, 0, stream>>>(fhb, fw2t + (size_t)i*D_*FF_,
        fb2 + i*D_, nullptr, nullptr, ofb, M_, D_, FF_);
    add_ln_kernel<<<M_/4, 256, 0, stream>>>(hf, ofb, g2 + i*D_, b2 + i*D_,
        (i == NL_-1) ? out : hf, hb);
  }
}

// Round 7
// 799.616 us; speedup vs baseline: 1.0839x; 1.0839x over previous
//
#include <hip/hip_runtime.h>
#include <math.h>

typedef unsigned short u16;
typedef unsigned int   u32;
typedef __bf16 bf16_t;
typedef bf16_t bf16x8 __attribute__((ext_vector_type(8)));
typedef float  f32x4  __attribute__((ext_vector_type(4)));
typedef u16    u16x8  __attribute__((ext_vector_type(8)));
typedef u16    u16x4  __attribute__((ext_vector_type(4)));

#define B_   8
#define L_   1024
#define DIN_ 32
#define D_   512
#define H_   8
#define NL_  6
#define FF_  64
#define M_   (B_*L_)    // 8192
#define DD_  (D_*D_)    // 262144

#define PE_COEF (-0.017988946039015984f)   // -ln(10000)/512
#define SC2     (0.18033688011112042f)     // 0.125 * log2(e)

__device__ __forceinline__ u16 f2bf(float f) {
  u32 u = __builtin_bit_cast(u32, f);
  u32 r = (u + 0x7FFFu + ((u >> 16) & 1u)) >> 16;
  return (u16)r;
}
__device__ __forceinline__ u16 f2bf_fast(float f) {   // positive values (P in [0,1])
  u32 u = __builtin_bit_cast(u32, f);
  return (u16)((u + 0x8000u) >> 16);
}
__device__ __forceinline__ float bf2f(u16 v) {
  u32 u = ((u32)v) << 16;
  return __builtin_bit_cast(float, u);
}

#define GLOAD_LDS16(gp, lp) \
  __builtin_amdgcn_global_load_lds((const __attribute__((address_space(1))) u32*)(gp), \
                                   (__attribute__((address_space(3))) u32*)(lp), 16, 0, 0)

// ---------------- fused weight transpose + f32->bf16 for all 512x512 sets ----------------
// z: 0-5 wq, 6-11 wk, 12-17 wv, 18-23 wo, 24 emb_w2.  W[K][N] -> Wt[N][K].
__global__ __launch_bounds__(256) void transpose_all(const float* __restrict__ wq, const float* __restrict__ wk,
                                                     const float* __restrict__ wv, const float* __restrict__ wo,
                                                     const float* __restrict__ ew2,
                                                     u16* __restrict__ qkvt, u16* __restrict__ wot,
                                                     u16* __restrict__ ew2t) {
  __shared__ float tile[32][33];
  int z = blockIdx.z;
  const float* src;
  u16* dst;
  if (z < 18) {
    int grp = z / 6, i = z % 6;
    src = (grp == 0 ? wq : grp == 1 ? wk : wv) + (size_t)i*DD_;
    dst = qkvt + (size_t)i*3*DD_ + (size_t)grp*DD_;
  } else if (z < 24) {
    int i = z - 18;
    src = wo + (size_t)i*DD_;
    dst = wot + (size_t)i*DD_;
  } else {
    src = ew2; dst = ew2t;
  }
  int k0 = blockIdx.y * 32, n0 = blockIdx.x * 32;
  int tx = threadIdx.x & 31, ty = threadIdx.x >> 5;
  #pragma unroll
  for (int i = 0; i < 4; ++i)
    tile[ty + i*8][tx] = src[(size_t)(k0 + ty + i*8)*512 + n0 + tx];
  __syncthreads();
  #pragma unroll
  for (int i = 0; i < 4; ++i)
    dst[(size_t)(n0 + ty + i*8)*512 + k0 + tx] = f2bf(tile[tx][ty + i*8]);
}

// ---------------- generic weight transpose (fw1/fw2) ----------------
__global__ __launch_bounds__(256) void transpose_k(const float* __restrict__ W, u16* __restrict__ Wt,
                                                   int K, int N, size_t in_zs, size_t out_zs) {
  __shared__ float tile[32][33];
  size_t mi = (size_t)blockIdx.z * in_zs;
  size_t mo = (size_t)blockIdx.z * out_zs;
  int k0 = blockIdx.y * 32, n0 = blockIdx.x * 32;
  int tx = threadIdx.x & 31, ty = threadIdx.x >> 5;
  #pragma unroll
  for (int i = 0; i < 4; ++i)
    tile[ty + i*8][tx] = W[mi + (size_t)(k0 + ty + i*8)*N + n0 + tx];
  __syncthreads();
  #pragma unroll
  for (int i = 0; i < 4; ++i)
    Wt[mo + (size_t)(n0 + ty + i*8)*K + k0 + tx] = f2bf(tile[tx][ty + i*8]);
}

// ---------------- embedding MLP stage 1 + LayerNorm (bf16 out) ----------------
__global__ __launch_bounds__(256) void emb1_ln_kernel(const float* __restrict__ x, const float* __restrict__ W1,
                               const float* __restrict__ b1, const float* __restrict__ g,
                               const float* __restrict__ beta, u16* __restrict__ outb) {
  __shared__ float xs[DIN_];
  __shared__ float red[4];
  int m = blockIdx.x;
  int tid = threadIdx.x;
  if (tid < DIN_) xs[tid] = x[m*DIN_ + tid];
  __syncthreads();
  float v[2];
  #pragma unroll
  for (int r = 0; r < 2; ++r) {
    int n = tid + r*256;
    float acc = b1[n];
    #pragma unroll
    for (int k = 0; k < DIN_; ++k) acc += xs[k] * W1[k*D_ + n];
    v[r] = fmaxf(acc, 0.f);
  }
  float s = v[0] + v[1];
  #pragma unroll
  for (int off = 32; off > 0; off >>= 1) s += __shfl_down(s, off, 64);
  int wid = tid >> 6;
  if ((tid & 63) == 0) red[wid] = s;
  __syncthreads();
  float mean = (red[0] + red[1] + red[2] + red[3]) * (1.f/D_);
  float d0 = v[0] - mean, d1 = v[1] - mean;
  float vv = d0*d0 + d1*d1;
  #pragma unroll
  for (int off = 32; off > 0; off >>= 1) vv += __shfl_down(vv, off, 64);
  __syncthreads();
  if ((tid & 63) == 0) red[wid] = vv;
  __syncthreads();
  float var = (red[0] + red[1] + red[2] + red[3]) * (1.f/D_);
  float rstd = rsqrtf(var + 1e-5f);
  outb[(size_t)m*D_ + tid]       = f2bf(d0*rstd*g[tid]       + beta[tid]);
  outb[(size_t)m*D_ + tid + 256] = f2bf(d1*rstd*g[tid + 256] + beta[tid + 256]);
}

// ---------------- residual add + LayerNorm, one wave per row ----------------
__global__ __launch_bounds__(256) void add_ln_kernel(const float* __restrict__ hin, const u16* __restrict__ res,
                              const float* __restrict__ g, const float* __restrict__ b,
                              float* __restrict__ outf, u16* __restrict__ outb) {
  int w = threadIdx.x >> 6, lane = threadIdx.x & 63;
  int m = blockIdx.x * 4 + w;
  const float* hr = hin + (size_t)m*D_;
  const u16*   rr = res + (size_t)m*D_;
  float v[8];
  float s = 0.f;
  #pragma unroll
  for (int i = 0; i < 8; ++i) {
    int c = lane + i*64;
    v[i] = hr[c] + bf2f(rr[c]);
    s += v[i];
  }
  #pragma unroll
  for (int off = 32; off > 0; off >>= 1) s += __shfl_xor(s, off, 64);
  float mean = s * (1.f/D_);
  float vs = 0.f;
  #pragma unroll
  for (int i = 0; i < 8; ++i) { v[i] -= mean; vs += v[i]*v[i]; }
  #pragma unroll
  for (int off = 32; off > 0; off >>= 1) vs += __shfl_xor(vs, off, 64);
  float rstd = rsqrtf(vs * (1.f/D_) + 1e-5f);
  #pragma unroll
  for (int i = 0; i < 8; ++i) {
    int c = lane + i*64;
    float o = v[i]*rstd*g[c] + b[c];
    outf[(size_t)m*D_ + c] = o;
    outb[(size_t)m*D_ + c] = f2bf(o);
  }
}

// ---------------- bf16 MFMA GEMM, BK=32, NBUF=3, depth-2 counted-vmcnt (R4 structure) ----------------
// C = A[M,K] @ Bt[N,K]^T.  EPI bits: 1=+bias, 2=relu, 4=+PE.  WF: f32 out, WB: bf16 out.
template<int BM, int BN, int EPI, bool WF, bool WB>
__global__ __launch_bounds__(256) void mgemm(const u16* __restrict__ A, const u16* __restrict__ Bt,
                            const float* __restrict__ bias, const float* __restrict__ extra,
                            float* __restrict__ Cf, u16* __restrict__ Cb,
                            int M, int N, int K) {
  constexpr int NBUF = 3;
  constexpr int LPT = BM/64 + BN/64;         // global_load_lds per thread per stage
  __shared__ __align__(16) u16 As[NBUF][BM*32];
  __shared__ __align__(16) u16 Bs[NBUF][BN*32];
  const int WR = BM/2, WC = BN/2, MR = WR/16, NR = WC/16;
  // XCD-chunked swizzle (all grids have nwg % 8 == 0)
  int nx = gridDim.x;
  int nwg = nx * gridDim.y;
  int flat = blockIdx.y * nx + blockIdx.x;
  int wid = (flat & 7) * (nwg >> 3) + (flat >> 3);
  int bm = (wid / nx) * BM, bn = (wid % nx) * BN;
  int tid = threadIdx.x, w = tid >> 6, l = tid & 63;
  int wr = w >> 1, wc = w & 1;
  int lq = l & 15, lg = l >> 4;
  f32x4 acc[MR][NR];
  #pragma unroll
  for (int m = 0; m < MR; ++m)
    #pragma unroll
    for (int n = 0; n < NR; ++n) acc[m][n] = f32x4{0.f,0.f,0.f,0.f};

  int srow = w*16 + (l >> 2);
  int scol = (l & 3)*8;

  auto stage = [&](int t, int bi) {
    int k0 = t << 5;
    #pragma unroll
    for (int i = 0; i < BM/64; ++i)
      GLOAD_LDS16(A + (size_t)(bm + i*64 + srow)*K + k0 + scol, &As[bi][i*2048 + w*512]);
    #pragma unroll
    for (int i = 0; i < BN/64; ++i)
      GLOAD_LDS16(Bt + (size_t)(bn + i*64 + srow)*K + k0 + scol, &Bs[bi][i*2048 + w*512]);
  };

  int nk = K >> 5;
  stage(0, 0);
  if (nk > 1) stage(1, 1);
  int bi = 0;
  #pragma unroll 1
  for (int t = 0; t < nk; ++t) {
    // wait until stage(t) landed; keep stage(t+1) in flight (counted vmcnt, never 0 mid-loop)
    if (t + 1 < nk) {
      if constexpr (LPT == 2)      asm volatile("s_waitcnt vmcnt(2)" ::: "memory");
      else if constexpr (LPT == 3) asm volatile("s_waitcnt vmcnt(3)" ::: "memory");
      else if constexpr (LPT == 4) asm volatile("s_waitcnt vmcnt(4)" ::: "memory");
      else                         asm volatile("s_waitcnt vmcnt(0)" ::: "memory");
    } else {
      asm volatile("s_waitcnt vmcnt(0)" ::: "memory");
    }
    __builtin_amdgcn_s_barrier();            // all waves' stage(t) visible; compute(t-1) done
    __builtin_amdgcn_sched_barrier(0);       // fence: nothing hoists above the barrier
    if (t + 2 < nk) {
      int b2 = bi + 2; if (b2 >= NBUF) b2 -= NBUF;
      stage(t + 2, b2);                      // overwrites buf of t-1 (readers done)
    }
    bf16x8 af[MR], bfr[NR];
    #pragma unroll
    for (int m = 0; m < MR; ++m)
      af[m] = *(const bf16x8*)&As[bi][(wr*WR + m*16 + lq)*32 + lg*8];
    #pragma unroll
    for (int n = 0; n < NR; ++n)
      bfr[n] = *(const bf16x8*)&Bs[bi][(wc*WC + n*16 + lq)*32 + lg*8];
    #pragma unroll
    for (int m = 0; m < MR; ++m)
      #pragma unroll
      for (int n = 0; n < NR; ++n)
        acc[m][n] = __builtin_amdgcn_mfma_f32_16x16x32_bf16(af[m], bfr[n], acc[m][n], 0, 0, 0);
    bi = (bi + 1 == NBUF) ? 0 : bi + 1;
  }

  #pragma unroll
  for (int m = 0; m < MR; ++m) {
    #pragma unroll
    for (int n = 0; n < NR; ++n) {
      #pragma unroll
      for (int r = 0; r < 4; ++r) {
        int row = bm + wr*WR + m*16 + lg*4 + r;
        int col = bn + wc*WC + n*16 + lq;
        float v = acc[m][n][r];
        if (EPI & 1) v += bias[col];
        if (EPI & 2) v = fmaxf(v, 0.f);
        if (EPI & 4) {
          float fr  = __expf((float)(col & ~1) * PE_COEF);
          float arg = extra[row] * fr;
          v += (col & 1) ? cosf(arg) : sinf(arg);
        }
        if (WF) Cf[(size_t)row*N + col] = v;
        if (WB) Cb[(size_t)row*N + col] = f2bf(v);
      }
    }
  }
}

// ---------------- fused FF: out = LN(h + relu(h@fw1+b1)@fw2 + b2) ----------------
// 256 blocks x 32 rows, 512 threads (8 waves). A staged via swizzled global_load_lds.
__global__ __launch_bounds__(512) void ff_fused(const u16* __restrict__ Ain,
        const u16* __restrict__ fw1t, const float* __restrict__ fb1,
        const u16* __restrict__ fw2t, const float* __restrict__ fb2,
        const float* __restrict__ hres, const float* __restrict__ g,
        const float* __restrict__ bet, float* __restrict__ outf, u16* __restrict__ outb) {
  __shared__ __align__(16) u16 Asw[32*512];    // swizzled [32][512], 32KB
  __shared__ __align__(16) u16 fls[32*72];     // f [32][72] bf16
  __shared__ float part[32][4];
  int tid = threadIdx.x, w = tid >> 6, l = tid & 63;
  int lq = l & 15, lg = l >> 4;
  int bm = blockIdx.x * 32;
  // stage A: LDS linear, global source pre-swizzled (slot ^= row&7, 16B slots)
  #pragma unroll
  for (int i = 0; i < 4; ++i) {
    int lam = tid + i*512;          // 16B units
    int row = lam >> 6;
    int slot = lam & 63;
    int sslot = slot ^ (row & 7);
    GLOAD_LDS16(Ain + (size_t)(bm + row)*512 + sslot*8, Asw + lam*8);
  }
  asm volatile("s_waitcnt vmcnt(0)" ::: "memory");
  __syncthreads();
  // phase 1: f[32][64] = relu(A @ fw1t^T + b1); wave w computes tile (w>>2, w&3)
  {
    int mt = w >> 2, nt = w & 3;
    f32x4 facc = f32x4{0.f,0.f,0.f,0.f};
    const u16* bp = fw1t + (size_t)(nt*16 + lq)*512;
    int arow = mt*16 + lq;
    #pragma unroll
    for (int ks = 0; ks < 16; ++ks) {
      int slot = (ks*4 + lg) ^ (arow & 7);
      bf16x8 a = *(const bf16x8*)&Asw[arow*512 + slot*8];
      bf16x8 b = *(const bf16x8*)&bp[ks*32 + lg*8];
      facc = __builtin_amdgcn_mfma_f32_16x16x32_bf16(a, b, facc, 0, 0, 0);
    }
    float bias = fb1[nt*16 + lq];
    #pragma unroll
    for (int r = 0; r < 4; ++r)
      fls[(mt*16 + lg*4 + r)*72 + nt*16 + lq] = f2bf(fmaxf(facc[r] + bias, 0.f));
  }
  __syncthreads();
  // phase 2: out[32][512] = f @ fw2t^T; wave w: rows (w>>2)*16, cols (w&3)*128
  int m0 = (w >> 2) * 16;
  int n0 = (w & 3) * 128;
  f32x4 acc[8];
  #pragma unroll
  for (int n = 0; n < 8; ++n) acc[n] = f32x4{0.f,0.f,0.f,0.f};
  #pragma unroll
  for (int ks = 0; ks < 2; ++ks) {
    bf16x8 a = *(const bf16x8*)&fls[(m0 + lq)*72 + ks*32 + lg*8];
    #pragma unroll
    for (int n = 0; n < 8; ++n) {
      bf16x8 b = *(const bf16x8*)&fw2t[(size_t)(n0 + n*16 + lq)*64 + ks*32 + lg*8];
      acc[n] = __builtin_amdgcn_mfma_f32_16x16x32_bf16(a, b, acc[n], 0, 0, 0);
    }
  }
  // epilogue: +bias +residual, cross-wave LN over 512 cols
  float v[8][4];
  float psum[4] = {0.f,0.f,0.f,0.f};
  #pragma unroll
  for (int n = 0; n < 8; ++n) {
    int col = n0 + n*16 + lq;
    float bias = fb2[col];
    #pragma unroll
    for (int r = 0; r < 4; ++r) {
      int row = bm + m0 + lg*4 + r;
      float t = acc[n][r] + bias + hres[(size_t)row*512 + col];
      v[n][r] = t;
      psum[r] += t;
    }
  }
  #pragma unroll
  for (int off = 1; off <= 8; off <<= 1)
    #pragma unroll
    for (int r = 0; r < 4; ++r) psum[r] += __shfl_xor(psum[r], off);
  if (lq == 0)
    #pragma unroll
    for (int r = 0; r < 4; ++r) part[m0 + lg*4 + r][w & 3] = psum[r];
  __syncthreads();
  float mean[4];
  #pragma unroll
  for (int r = 0; r < 4; ++r) {
    int row = m0 + lg*4 + r;
    mean[r] = (part[row][0] + part[row][1] + part[row][2] + part[row][3]) * (1.f/512.f);
  }
  __syncthreads();
  float pv[4] = {0.f,0.f,0.f,0.f};
  #pragma unroll
  for (int n = 0; n < 8; ++n)
    #pragma unroll
    for (int r = 0; r < 4; ++r) { v[n][r] -= mean[r]; pv[r] += v[n][r]*v[n][r]; }
  #pragma unroll
  for (int off = 1; off <= 8; off <<= 1)
    #pragma unroll
    for (int r = 0; r < 4; ++r) pv[r] += __shfl_xor(pv[r], off);
  if (lq == 0)
    #pragma unroll
    for (int r = 0; r < 4; ++r) part[m0 + lg*4 + r][w & 3] = pv[r];
  __syncthreads();
  #pragma unroll
  for (int r = 0; r < 4; ++r) {
    int lrow = m0 + lg*4 + r;
    float var = (part[lrow][0] + part[lrow][1] + part[lrow][2] + part[lrow][3]) * (1.f/512.f);
    float rstd = rsqrtf(var + 1e-5f);
    int row = bm + lrow;
    #pragma unroll
    for (int n = 0; n < 8; ++n) {
      int col = n0 + n*16 + lq;
      float o = v[n][r]*rstd*g[col] + bet[col];
      outf[(size_t)row*512 + col] = o;
      outb[(size_t)row*512 + col] = f2bf(o);
    }
  }
}

// ---------------- MFMA causal flash attention, KVBLK=64, 1 barrier/tile ----------------
#define QS_ 1536
__global__ __launch_bounds__(256) void attn_kernel(const u16* __restrict__ Q, const u16* __restrict__ Kp,
                                                   const u16* __restrict__ V, u16* __restrict__ O) {
  __shared__ __align__(16) u16 Ks[2][64*72];     // [kv][d]  stride 72
  __shared__ __align__(16) u16 Vt[2][64*72];     // [d][kv]  stride 72
  __shared__ __align__(16) u16 Ps[4][16*72];     // per-wave [q][kv] stride 72
  int flat = blockIdx.y * 8 + blockIdx.x;        // grid (8,64), nwg=512
  int wid  = (flat & 7) * 64 + (flat >> 3);
  int pair = wid & 7, bh = wid >> 3;
  int b = bh >> 3, hh = bh & 7;
  int rowbase = b * L_, col0 = hh * 64;
  int tid = threadIdx.x, w = tid >> 6, l = tid & 63;
  int lq = l & 15, lg = l >> 4;

  int krow = tid >> 3, kseg = tid & 7;
  int vg = tid >> 5, vd2 = (tid & 31) * 2;

  u16x8 kr0, kr1;
  u32 vr[8];
  u16x8 oc16;
  #pragma unroll
  for (int i = 0; i < 8; ++i) oc16[i] = 0x3F80u;   // bf16 1.0
  const bf16x8 onesA = __builtin_bit_cast(bf16x8, oc16);

  #define LOADKV(t) { \
    kr0 = *(const u16x8*)&Kp[(size_t)(rowbase + (t)*64 + krow)*QS_ + col0 + kseg*8]; \
    kr1 = *(const u16x8*)&Kp[(size_t)(rowbase + (t)*64 + krow + 32)*QS_ + col0 + kseg*8]; \
    _Pragma("unroll") \
    for (int i_ = 0; i_ < 8; ++i_) \
      vr[i_] = *(const u32*)&V[(size_t)(rowbase + (t)*64 + vg*8 + i_)*QS_ + col0 + vd2]; }

  #define WRITE_LDS(bb) { \
    *(u16x8*)&Ks[bb][krow*72 + kseg*8]        = kr0; \
    *(u16x8*)&Ks[bb][(krow + 32)*72 + kseg*8] = kr1; \
    u16x8 vlo, vhi; \
    _Pragma("unroll") \
    for (int i_ = 0; i_ < 8; ++i_) { vlo[i_] = (u16)(vr[i_] & 0xffffu); vhi[i_] = (u16)(vr[i_] >> 16); } \
    *(u16x8*)&Vt[bb][vd2*72 + vg*8]     = vlo; \
    *(u16x8*)&Vt[bb][(vd2+1)*72 + vg*8] = vhi; }

  LOADKV(0);

  #pragma unroll 1
  for (int half = 0; half < 2; ++half) {
    int qt = half ? (15 - pair) : pair;
    int qrow = rowbase + qt*64 + w*16 + lq;
    bf16x8 qa0 = *(const bf16x8*)&Q[(size_t)qrow*QS_ + col0 + lg*8];
    bf16x8 qa1 = *(const bf16x8*)&Q[(size_t)qrow*QS_ + col0 + 32 + lg*8];
    float m_s[4];
    f32x4 o[4], o4;
    #pragma unroll
    for (int r = 0; r < 4; ++r) m_s[r] = -1e30f;
    #pragma unroll
    for (int n = 0; n < 4; ++n) o[n] = f32x4{0.f,0.f,0.f,0.f};
    o4 = f32x4{0.f,0.f,0.f,0.f};

    __syncthreads();            // prior half's readers of LDS[0] done
    WRITE_LDS(0);               // tile 0 of this half (regs loaded previously)

    #pragma unroll 1
    for (int kt = 0; kt <= qt; ++kt) {
      int buf = kt & 1;
      __syncthreads();          // LDS[buf] writes visible; prev iter's buf^1 readers done
      int nt = (kt < qt) ? (kt + 1) : (half == 0 ? 0 : -1);
      if (nt >= 0) LOADKV(nt);  // flies under compute

      f32x4 t4[4];
      __builtin_amdgcn_s_setprio(1);
      #pragma unroll
      for (int f = 0; f < 4; ++f) {
        bf16x8 k0 = *(const bf16x8*)&Ks[buf][(f*16 + lq)*72 + lg*8];
        bf16x8 k1 = *(const bf16x8*)&Ks[buf][(f*16 + lq)*72 + 32 + lg*8];
        f32x4 z = f32x4{0.f,0.f,0.f,0.f};
        z = __builtin_amdgcn_mfma_f32_16x16x32_bf16(qa0, k0, z, 0, 0, 0);
        z = __builtin_amdgcn_mfma_f32_16x16x32_bf16(qa1, k1, z, 0, 0, 0);
        #pragma unroll
        for (int r = 0; r < 4; ++r) t4[f][r] = z[r] * SC2;
      }
      __builtin_amdgcn_s_setprio(0);
      if (kt == qt) {
        #pragma unroll
        for (int f = 0; f < 4; ++f) {
          int kvg = f*16 + lq;
          #pragma unroll
          for (int r = 0; r < 4; ++r)
            if (kvg > w*16 + lg*4 + r) t4[f][r] = -1e30f;
        }
      }
      float tm[4];
      bool need = false;
      #pragma unroll
      for (int r = 0; r < 4; ++r) {
        float vv = fmaxf(fmaxf(t4[0][r], t4[1][r]), fmaxf(t4[2][r], t4[3][r]));
        vv = fmaxf(vv, __shfl_xor(vv, 1));
        vv = fmaxf(vv, __shfl_xor(vv, 2));
        vv = fmaxf(vv, __shfl_xor(vv, 4));
        vv = fmaxf(vv, __shfl_xor(vv, 8));
        tm[r] = vv;
        need = need || (vv > m_s[r]);
      }
      if (__any(need)) {
        float corr[4];
        #pragma unroll
        for (int r = 0; r < 4; ++r) {
          float mn = fmaxf(m_s[r], tm[r]);
          corr[r] = __builtin_amdgcn_exp2f(m_s[r] - mn);
          m_s[r] = mn;
        }
        int bsrc = (lq >> 2)*16 + lq;
        float c0 = __shfl(corr[0], bsrc);
        float c1 = __shfl(corr[1], bsrc);
        float c2 = __shfl(corr[2], bsrc);
        float c3 = __shfl(corr[3], bsrc);
        float cb = (lq & 2) ? ((lq & 1) ? c3 : c2) : ((lq & 1) ? c1 : c0);
        #pragma unroll
        for (int n = 0; n < 4; ++n)
          #pragma unroll
          for (int r = 0; r < 4; ++r) o[n][r] *= cb;
        #pragma unroll
        for (int r = 0; r < 4; ++r) o4[r] *= cb;
      }
      #pragma unroll
      for (int r = 0; r < 4; ++r) {
        int prow = (lg*4 + r)*72;
        Ps[w][prow + lq]      = f2bf_fast(__builtin_amdgcn_exp2f(t4[0][r] - m_s[r]));
        Ps[w][prow + 16 + lq] = f2bf_fast(__builtin_amdgcn_exp2f(t4[1][r] - m_s[r]));
        Ps[w][prow + 32 + lq] = f2bf_fast(__builtin_amdgcn_exp2f(t4[2][r] - m_s[r]));
        Ps[w][prow + 48 + lq] = f2bf_fast(__builtin_amdgcn_exp2f(t4[3][r] - m_s[r]));
      }
      bf16x8 pB0 = *(const bf16x8*)&Ps[w][lq*72 + lg*8];
      bf16x8 pB1 = *(const bf16x8*)&Ps[w][lq*72 + 32 + lg*8];
      __builtin_amdgcn_s_setprio(1);
      o4 = __builtin_amdgcn_mfma_f32_16x16x32_bf16(onesA, pB0, o4, 0, 0, 0);
      o4 = __builtin_amdgcn_mfma_f32_16x16x32_bf16(onesA, pB1, o4, 0, 0, 0);
      #pragma unroll
      for (int n = 0; n < 4; ++n) {
        bf16x8 vA0 = *(const bf16x8*)&Vt[buf][(n*16 + lq)*72 + lg*8];
        bf16x8 vA1 = *(const bf16x8*)&Vt[buf][(n*16 + lq)*72 + 32 + lg*8];
        o[n] = __builtin_amdgcn_mfma_f32_16x16x32_bf16(vA0, pB0, o[n], 0, 0, 0);
        o[n] = __builtin_amdgcn_mfma_f32_16x16x32_bf16(vA1, pB1, o[n], 0, 0, 0);
      }
      __builtin_amdgcn_s_setprio(0);
      if (kt < qt) WRITE_LDS(buf ^ 1);   // next tile; visible after next barrier
    }
    float inv = 1.f / o4[0];
    #pragma unroll
    for (int n = 0; n < 4; ++n) {
      u16x4 pk;
      #pragma unroll
      for (int r = 0; r < 4; ++r) pk[r] = f2bf(o[n][r] * inv);
      *(u16x4*)&O[(size_t)(rowbase + qt*64 + w*16 + lq)*D_ + col0 + n*16 + lg*4] = pk;
    }
  }
  #undef LOADKV
  #undef WRITE_LDS
}

// ---------------- host ----------------
extern "C" void kernel_launch(void* const* d_in, const int* in_sizes, int n_in,
                              void* d_out, int out_size, void* d_ws, size_t ws_size,
                              hipStream_t stream) {
  (void)in_sizes; (void)n_in; (void)out_size; (void)ws_size;
  const float* x      = (const float*)d_in[0];
  const float* obs    = (const float*)d_in[2];
  const float* emb_w1 = (const float*)d_in[3];
  const float* emb_b1 = (const float*)d_in[4];
  const float* emb_g  = (const float*)d_in[5];
  const float* emb_be = (const float*)d_in[6];
  const float* emb_w2 = (const float*)d_in[7];
  const float* emb_b2 = (const float*)d_in[8];
  const float* wq  = (const float*)d_in[9];
  const float* wk  = (const float*)d_in[10];
  const float* wv  = (const float*)d_in[11];
  const float* wo  = (const float*)d_in[12];
  const float* bo  = (const float*)d_in[13];
  const float* fw1 = (const float*)d_in[14];
  const float* fb1 = (const float*)d_in[15];
  const float* fw2 = (const float*)d_in[16];
  const float* fb2 = (const float*)d_in[17];
  const float* g1  = (const float*)d_in[18];
  const float* b1  = (const float*)d_in[19];
  const float* g2  = (const float*)d_in[20];
  const float* b2  = (const float*)d_in[21];
  float* out = (float*)d_out;

  float* hf  = (float*)d_ws;                  // [M,D] f32 residual
  u16* hb    = (u16*)(hf + (size_t)M_*D_);    // [M,D] bf16 copy of hf
  u16* qkvb  = hb + (size_t)M_*D_;            // [M,3D] bf16 fused qkv
  u16* ob    = qkvb + (size_t)M_*3*D_;        // [M,D] bf16 (emb1 out / attn out)
  u16* ofb   = ob + (size_t)M_*D_;            // [M,D] bf16 branch out
  u16* qkvt  = ofb + (size_t)M_*D_;           // [NL][3][D][D] bf16 (W^T)
  u16* wot   = qkvt + (size_t)18*DD_;         // [NL][D][D]
  u16* ew2t  = wot + (size_t)6*DD_;           // [D][D]
  u16* fw1t  = ew2t + (size_t)DD_;            // [NL][FF][D]
  u16* fw2t  = fw1t + (size_t)6*D_*FF_;       // [NL][D][FF]

  transpose_all<<<dim3(16,16,25), 256, 0, stream>>>(wq, wk, wv, wo, emb_w2, qkvt, wot, ew2t);
  transpose_k<<<dim3(2,16,6),  256, 0, stream>>>(fw1, fw1t, 512,  64, (size_t)D_*FF_, (size_t)D_*FF_);
  transpose_k<<<dim3(16,2,6),  256, 0, stream>>>(fw2, fw2t,  64, 512, (size_t)D_*FF_, (size_t)D_*FF_);

  emb1_ln_kernel<<<M_, 256, 0, stream>>>(x, emb_w1, emb_b1, emb_g, emb_be, ob);
  mgemm<128,128,5,true,true><<<dim3(4,64), 256, 0, stream>>>(ob, ew2t, emb_b2, obs, hf, hb, M_, D_, D_);

  for (int i = 0; i < NL_; ++i) {
    mgemm<128,128,0,false,true><<<dim3(12,64), 256, 0, stream>>>(hb, qkvt + (size_t)i*3*DD_,
        nullptr, nullptr, nullptr, qkvb, M_, 3*D_, D_);
    attn_kernel<<<dim3(8, B_*H_), 256, 0, stream>>>(qkvb, qkvb + D_, qkvb + 2*D_, ob);
    mgemm<128,128,1,false,true><<<dim3(4,64), 256, 0, stream>>>(ob, wot + (size_t)i*DD_,
        bo + i*D_, nullptr, nullptr, ofb, M_, D_, D_);
    add_ln_kernel<<<M_/4, 256, 0, stream>>>(hf, ofb, g1 + i*D_, b1 + i*D_, hf, hb);
    ff_fused<<<M_/32, 512, 0, stream>>>(hb, fw1t + (size_t)i*D_*FF_, fb1 + i*FF_,
        fw2t + (size_t)i*D_*FF_, fb2 + i*D_, hf, g2 + i*D_, b2 + i*D_,
        (i == NL_-1) ? out : hf, hb);
  }
}